// Round 9
// baseline (33.089 us; speedup 1.0000x reference)
//
#include <hip/hip_runtime.h>

typedef float v4f __attribute__((ext_vector_type(4)));

#define LPTS 2048
#define BIGV 1e12f

// f(r) = WALL * softplus((4-r)/0.2); smoothstep dropped (f<=2e-8 where sw<1).
// softplus in log2 domain: ln2 * log2(1 + exp2(28.8539008 - 7.2134752*r)).
// Triangle counted once -> final scale 2 * WALL * ln2 = 13.86294361.

__device__ __forceinline__ float pterm(float d2) {
    const float r = __builtin_amdgcn_sqrtf(d2);
    const float e = __builtin_amdgcn_exp2f(fmaf(r, -7.2134752f, 28.8539008f));
    return __builtin_amdgcn_logf(1.0f + e);   // v_log_f32 == log2; ~0 for far pairs
}

// Row i vs j in [j0, 2047]; 4 consecutive j per lane, anchored at the top so all
// ds_read_b128 stay 16B-aligned. j0 is wave-uniform.
__device__ __forceinline__ float row_seg4(const float* __restrict__ s, int j0, int lane,
                                          float xi, float yi, float zi) {
    const int n     = 2048 - j0;     // uniform
    const int fullc = n >> 8;        // unmasked 256-pair chunks
    const int rem   = n & 255;
    const int base  = 2044 - 4 * lane;   // multiple of 4 -> 16B aligned
    float acc = 0.0f;

    for (int c = 0; c < fullc; ++c) {
        const int jb = base - 256 * c;                    // >= j0 + rem
        const v4f xv = *(const v4f*)(s + jb);             // ds_read_b128
        const v4f yv = *(const v4f*)(s + LPTS + jb);      // offset-imm +8192
        const v4f zv = *(const v4f*)(s + 2 * LPTS + jb);  // offset-imm +16384
        const v4f dx = xv - xi, dy = yv - yi, dz = zv - zi;
        v4f d2 = dx * dx;
        d2 = __builtin_elementwise_fma(dy, dy, d2);
        d2 = __builtin_elementwise_fma(dz, dz, d2);
        acc += pterm(d2.x); acc += pterm(d2.y);
        acc += pterm(d2.z); acc += pterm(d2.w);
    }
    if (rem) {                                            // single masked boundary chunk
        const int jbu = base - 256 * fullc;               // may be < j0, even < 0
        const int jcl = (jbu > 0) ? jbu : 0;              // clamp (stays 16B aligned)
        const v4f xv = *(const v4f*)(s + jcl);
        const v4f yv = *(const v4f*)(s + LPTS + jcl);
        const v4f zv = *(const v4f*)(s + 2 * LPTS + jcl);
        const v4f dx = xv - xi, dy = yv - yi, dz = zv - zi;
        v4f d2 = dx * dx;
        d2 = __builtin_elementwise_fma(dy, dy, d2);
        d2 = __builtin_elementwise_fma(dz, dz, d2);
        acc += pterm((jbu     >= j0) ? d2.x : BIGV);
        acc += pterm((jbu + 1 >= j0) ? d2.y : BIGV);
        acc += pterm((jbu + 2 >= j0) ? d2.z : BIGV);
        acc += pterm((jbu + 3 >= j0) ? d2.w : BIGV);
    }
    return acc;
}

__global__ __launch_bounds__(512, 8) void pair_energy_kernel(const float* __restrict__ R,
                                                             float* __restrict__ ws,
                                                             unsigned* __restrict__ cnt,
                                                             float* __restrict__ out) {
    __shared__ float lds[3 * LPTS];              // SoA x|y|z, 24 KB
    __shared__ float sp[8];
    __shared__ int   last;

    const int t    = threadIdx.x;
    const int wave = t >> 6;
    const int lane = t & 63;
    const int lb   = blockIdx.x & 127;           // 128 blocks per batch
    const int bb   = blockIdx.x >> 7;
    const float* Rb = R + (size_t)bb * (LPTS * 3);

    // stage: 3 coalesced float4 loads per thread, repacked AoS->SoA
    #pragma unroll
    for (int k = 0; k < 3; ++k) {
        const int f4 = t + 512 * k;
        const float4 v = ((const float4*)Rb)[f4];
        #pragma unroll
        for (int c = 0; c < 4; ++c) {
            const unsigned f = 4u * (unsigned)f4 + c;
            const unsigned p = f / 3u;           // magic-mul div
            const unsigned comp = f - 3u * p;
            lds[comp * LPTS + p] = ((const float*)&v)[c];
        }
    }
    __syncthreads();

    // one unit per wave: unit u pairs row A (i=u) with row B (i=2045-u), 2047 pairs
    const int u = __builtin_amdgcn_readfirstlane(lb * 8 + wave);
    float acc = 0.0f;
    if (u < 1023) {                              // u==1023 is a no-op unit
        const int iB = 2045 - u;
        acc  = row_seg4(lds, u + 2, lane,
                        lds[u],  lds[LPTS + u],  lds[2 * LPTS + u]);
        acc += row_seg4(lds, 2047 - u, lane,
                        lds[iB], lds[LPTS + iB], lds[2 * LPTS + iB]);
    }

    #pragma unroll
    for (int off = 32; off > 0; off >>= 1) acc += __shfl_xor(acc, off, 64);
    if (lane == 0) sp[wave] = acc;
    __syncthreads();

    if (t == 0) {
        float partial = sp[0];
        #pragma unroll
        for (int w = 1; w < 8; ++w) partial += sp[w];
        ws[blockIdx.x] = partial;                // plain store, then release fence
        __threadfence();                         // device-scope: publish partial
        const unsigned old = atomicAdd(&cnt[bb], 1u);
        last = (old == 127u) ? 1 : 0;
    }
    __syncthreads();

    if (last && wave == 0) {                     // last-arriving block: parallel finish
        __threadfence();                         // acquire
        volatile const float* wv = ws + bb * 128;
        float s = wv[lane] + wv[64 + lane];      // 128 partials, 2/lane, parallel
        #pragma unroll
        for (int off = 32; off > 0; off >>= 1) s += __shfl_xor(s, off, 64);
        if (lane == 0) out[bb] = s * 13.86294361f;   // 2 * WALL * ln2
    }
}

extern "C" void kernel_launch(void* const* d_in, const int* in_sizes, int n_in,
                              void* d_out, int out_size, void* d_ws, size_t ws_size,
                              hipStream_t stream) {
    (void)n_in; (void)out_size; (void)ws_size;
    const float* R = (const float*)d_in[0];
    float* out = (float*)d_out;
    float* ws  = (float*)d_ws;

    const int B = in_sizes[0] / (LPTS * 3);
    const int nblk = B * 128;                      // 128 blocks per batch, 4 blocks/CU
    unsigned* cnt = (unsigned*)(ws + nblk);        // counters after partials

    (void)hipMemsetAsync(cnt, 0, (size_t)B * sizeof(unsigned), stream);
    pair_energy_kernel<<<nblk, 512, 0, stream>>>(R, ws, cnt, out);
}

// Round 10
// 16.640 us; speedup vs baseline: 1.9885x; 1.9885x over previous
//
#include <hip/hip_runtime.h>

typedef float v4f __attribute__((ext_vector_type(4)));

#define LPTS 2048
#define BIGV 1e12f

// f(r) = WALL * softplus((4-r)/0.2); smoothstep dropped (f<=2e-8 where sw<1).
// softplus(x)/ln2 = log2(1+2^s), s = 28.8539008 - 7.2134752*r.
// Identity: log2(1+2^s) = max(s,0) + log2(1+2^-|s|); correction via cubic in
// u = exp2(-|s|): u*(1.442695 - 0.64838u + 0.20568u^2)  (exact at u->0, u=1;
// |err| < 0.004 log2-units, only in the thin r~4 shell -> total err O(1e2)).
// Triangle counted once -> final scale 2 * WALL * ln2 = 13.86294361.

#define PC1 1.442695f
#define PC2 -0.64838f
#define PC3 0.20568f

__device__ __forceinline__ void pterm4(v4f d2, v4f& accm, v4f& accp) {
    v4f s;
    s.x = fmaf(__builtin_amdgcn_sqrtf(d2.x), -7.2134752f, 28.8539008f);
    s.y = fmaf(__builtin_amdgcn_sqrtf(d2.y), -7.2134752f, 28.8539008f);
    s.z = fmaf(__builtin_amdgcn_sqrtf(d2.z), -7.2134752f, 28.8539008f);
    s.w = fmaf(__builtin_amdgcn_sqrtf(d2.w), -7.2134752f, 28.8539008f);
    v4f u;
    u.x = __builtin_amdgcn_exp2f(-fabsf(s.x));   // -abs folds into v_exp modifier
    u.y = __builtin_amdgcn_exp2f(-fabsf(s.y));
    u.z = __builtin_amdgcn_exp2f(-fabsf(s.z));
    u.w = __builtin_amdgcn_exp2f(-fabsf(s.w));
    const v4f zero = {0.0f, 0.0f, 0.0f, 0.0f};
    const v4f c1 = {PC1, PC1, PC1, PC1};
    const v4f c2 = {PC2, PC2, PC2, PC2};
    const v4f c3 = {PC3, PC3, PC3, PC3};
    accm += __builtin_elementwise_max(s, zero);          // pk_max
    v4f t = __builtin_elementwise_fma(u, c3, c2);        // pk_fma
    t = __builtin_elementwise_fma(u, t, c1);             // pk_fma
    accp = __builtin_elementwise_fma(u, t, accp);        // p = u*t folded into acc
}

// Row i vs j in [j0, 2047]; 4 consecutive j per lane, anchored at the top so all
// ds_read_b128 stay 16B-aligned. j0 is wave-uniform.
__device__ __forceinline__ void row_seg4(const float* __restrict__ s, int j0, int lane,
                                         float xi, float yi, float zi,
                                         v4f& accm, v4f& accp) {
    const int n     = 2048 - j0;     // uniform
    const int fullc = n >> 8;        // unmasked 256-pair chunks
    const int rem   = n & 255;
    const int base  = 2044 - 4 * lane;   // multiple of 4 -> 16B aligned

    for (int c = 0; c < fullc; ++c) {
        const int jb = base - 256 * c;                    // >= j0 + rem
        const v4f xv = *(const v4f*)(s + jb);             // ds_read_b128
        const v4f yv = *(const v4f*)(s + LPTS + jb);      // offset-imm +8192
        const v4f zv = *(const v4f*)(s + 2 * LPTS + jb);  // offset-imm +16384
        const v4f dx = xv - xi, dy = yv - yi, dz = zv - zi;
        v4f d2 = dx * dx;
        d2 = __builtin_elementwise_fma(dy, dy, d2);
        d2 = __builtin_elementwise_fma(dz, dz, d2);
        pterm4(d2, accm, accp);
    }
    if (rem) {                                            // single masked boundary chunk
        const int jbu = base - 256 * fullc;               // may be < j0, even < 0
        const int jcl = (jbu > 0) ? jbu : 0;              // clamp (stays 16B aligned)
        const v4f xv = *(const v4f*)(s + jcl);
        const v4f yv = *(const v4f*)(s + LPTS + jcl);
        const v4f zv = *(const v4f*)(s + 2 * LPTS + jcl);
        const v4f dx = xv - xi, dy = yv - yi, dz = zv - zi;
        v4f d2 = dx * dx;
        d2 = __builtin_elementwise_fma(dy, dy, d2);
        d2 = __builtin_elementwise_fma(dz, dz, d2);
        d2.x = (jbu     >= j0) ? d2.x : BIGV;             // masked -> m=0, p=0
        d2.y = (jbu + 1 >= j0) ? d2.y : BIGV;
        d2.z = (jbu + 2 >= j0) ? d2.z : BIGV;
        d2.w = (jbu + 3 >= j0) ? d2.w : BIGV;
        pterm4(d2, accm, accp);
    }
}

__global__ __launch_bounds__(512, 8) void pair_energy_kernel(const float* __restrict__ R,
                                                             float* __restrict__ ws) {
    __shared__ float lds[3 * LPTS];              // SoA x|y|z, 24 KB
    __shared__ float sp[8];

    const int t    = threadIdx.x;
    const int wave = t >> 6;
    const int lane = t & 63;
    const int lb   = blockIdx.x & 127;           // 128 blocks per batch
    const int bb   = blockIdx.x >> 7;
    const float* Rb = R + (size_t)bb * (LPTS * 3);

    // stage: 3 coalesced float4 loads per thread, repacked AoS->SoA
    #pragma unroll
    for (int k = 0; k < 3; ++k) {
        const int f4 = t + 512 * k;
        const float4 v = ((const float4*)Rb)[f4];
        #pragma unroll
        for (int c = 0; c < 4; ++c) {
            const unsigned f = 4u * (unsigned)f4 + c;
            const unsigned p = f / 3u;           // magic-mul div
            const unsigned comp = f - 3u * p;
            lds[comp * LPTS + p] = ((const float*)&v)[c];
        }
    }
    __syncthreads();

    // one unit per wave: unit u pairs row A (i=u) with row B (i=2045-u), 2047 pairs
    const int u = __builtin_amdgcn_readfirstlane(lb * 8 + wave);
    v4f accm = {0.0f, 0.0f, 0.0f, 0.0f};
    v4f accp = {0.0f, 0.0f, 0.0f, 0.0f};
    if (u < 1023) {                              // u==1023 is a no-op unit
        const int iB = 2045 - u;
        row_seg4(lds, u + 2, lane,
                 lds[u],  lds[LPTS + u],  lds[2 * LPTS + u],  accm, accp);
        row_seg4(lds, 2047 - u, lane,
                 lds[iB], lds[LPTS + iB], lds[2 * LPTS + iB], accm, accp);
    }

    float acc = (accm.x + accm.y) + (accm.z + accm.w)
              + (accp.x + accp.y) + (accp.z + accp.w);
    #pragma unroll
    for (int off = 32; off > 0; off >>= 1) acc += __shfl_xor(acc, off, 64);
    if (lane == 0) sp[wave] = acc;
    __syncthreads();

    if (t == 0) {
        float partial = sp[0];
        #pragma unroll
        for (int w = 1; w < 8; ++w) partial += sp[w];
        ws[blockIdx.x] = partial;                // plain store, no atomics
    }
}

__global__ __launch_bounds__(128) void reduce_kernel(const float* __restrict__ ws,
                                                     float* __restrict__ out) {
    const int t = threadIdx.x;
    const int wave = t >> 6;
    const int lane = t & 63;
    float v = ws[blockIdx.x * 128 + t];
    #pragma unroll
    for (int off = 32; off > 0; off >>= 1) v += __shfl_xor(v, off, 64);
    __shared__ float sp[2];
    if (lane == 0) sp[wave] = v;
    __syncthreads();
    if (t == 0) out[blockIdx.x] = (sp[0] + sp[1]) * 13.86294361f;  // 2*WALL*ln2
}

extern "C" void kernel_launch(void* const* d_in, const int* in_sizes, int n_in,
                              void* d_out, int out_size, void* d_ws, size_t ws_size,
                              hipStream_t stream) {
    (void)n_in; (void)out_size; (void)ws_size;
    const float* R = (const float*)d_in[0];
    float* out = (float*)d_out;
    float* ws  = (float*)d_ws;

    const int B = in_sizes[0] / (LPTS * 3);
    pair_energy_kernel<<<B * 128, 512, 0, stream>>>(R, ws);  // 8 row-pair units / block
    reduce_kernel<<<B, 128, 0, stream>>>(ws, out);           // 128 partials / batch
}